// Round 6
// baseline (916.751 us; speedup 1.0000x reference)
//
#include <hip/hip_runtime.h>
#include <hip/hip_bf16.h>

// ---------- helpers ----------
__device__ inline unsigned fkey(float x) {
    unsigned u = __float_as_uint(x);
    return (u & 0x80000000u) ? ~u : (u | 0x80000000u);
}
__device__ inline float funkey(unsigned k) {
    unsigned u = (k & 0x80000000u) ? (k & 0x7FFFFFFFu) : ~k;
    return __uint_as_float(u);
}
__device__ inline float lrelu(float x) { return x > 0.f ? x : 0.2f * x; }

// ---------- LDS-tiled GEMM, K=64 fixed: O[n,c] = sum_k A[n,k]*B[k,c] ----------
__global__ __launch_bounds__(256, 4) void gemm_tiled(const float* __restrict__ A,
                                                     const float* __restrict__ B,
                                                     float* __restrict__ O, int N, int C) {
    __shared__ __align__(16) float As[64][68];
    __shared__ __align__(16) float Bs[64][64];
    int row0 = blockIdx.x * 64;
    int col0 = blockIdx.y * 64;
    int t = threadIdx.x;

    const float* Abase = A + (size_t)row0 * 64;
    int maxElems = (N - row0) * 64;
#pragma unroll
    for (int p = 0; p < 4; ++p) {
        int idx = t + p * 256;
        int r = idx >> 4, k0 = (idx & 15) << 2;
        float4 v = make_float4(0.f, 0.f, 0.f, 0.f);
        if (idx * 4 < maxElems) v = *reinterpret_cast<const float4*>(Abase + (size_t)idx * 4);
        As[r][k0] = v.x; As[r][k0 + 1] = v.y; As[r][k0 + 2] = v.z; As[r][k0 + 3] = v.w;
    }
#pragma unroll
    for (int p = 0; p < 4; ++p) {
        int idx = t + p * 256;
        int k = idx >> 4, c0 = (idx & 15) << 2;
        float4 v = *reinterpret_cast<const float4*>(B + (size_t)k * C + col0 + c0);
        *reinterpret_cast<float4*>(&Bs[k][c0]) = v;
    }
    __syncthreads();

    int c0 = (t & 15) * 4;
    int r0 = (t >> 4) * 4;
    float4 acc[4];
#pragma unroll
    for (int i = 0; i < 4; ++i) acc[i] = make_float4(0.f, 0.f, 0.f, 0.f);

#pragma unroll 2
    for (int k0 = 0; k0 < 64; k0 += 4) {
        float4 a[4], b[4];
#pragma unroll
        for (int i = 0; i < 4; ++i) a[i] = *reinterpret_cast<const float4*>(&As[r0 + i][k0]);
#pragma unroll
        for (int j = 0; j < 4; ++j) b[j] = *reinterpret_cast<const float4*>(&Bs[k0 + j][c0]);
#pragma unroll
        for (int i = 0; i < 4; ++i) {
            acc[i].x += a[i].x * b[0].x + a[i].y * b[1].x + a[i].z * b[2].x + a[i].w * b[3].x;
            acc[i].y += a[i].x * b[0].y + a[i].y * b[1].y + a[i].z * b[2].y + a[i].w * b[3].y;
            acc[i].z += a[i].x * b[0].z + a[i].y * b[1].z + a[i].z * b[2].z + a[i].w * b[3].z;
            acc[i].w += a[i].x * b[0].w + a[i].y * b[1].w + a[i].z * b[2].w + a[i].w * b[3].w;
        }
    }

#pragma unroll
    for (int i = 0; i < 4; ++i) {
        int row = row0 + r0 + i;
        if (row < N)
            *reinterpret_cast<float4*>(&O[(size_t)row * C + col0 + c0]) = acc[i];
    }
}

// ---------- fold attention vectors through W ----------
__global__ void fold_attn(const float* __restrict__ W, const float* __restrict__ al,
                          const float* __restrict__ ar, float* __restrict__ Walr,
                          int H, int D) {
    int k = blockIdx.x;
    int lane = threadIdx.x;
    int C = H * D;
    for (int h = 0; h < H; ++h) {
        float sl = 0.f, sr = 0.f;
        for (int d = lane; d < D; d += 64) {
            float w = W[(size_t)k * C + h * D + d];
            sl += w * al[h * D + d];
            sr += w * ar[h * D + d];
        }
        for (int off = 32; off; off >>= 1) {
            sl += __shfl_down(sl, off);
            sr += __shfl_down(sr, off);
        }
        if (lane == 0) {
            Walr[k * 2 * H + h] = sl;
            Walr[k * 2 * H + H + h] = sr;
        }
    }
}

// ---------- el/er from 64-dim input: one wave per node ----------
__global__ void attn_from_x(const float* __restrict__ in, const float* __restrict__ Walr,
                            float* __restrict__ el, float* __restrict__ er, int N, int H) {
    int lane = threadIdx.x & 63;
    int wib = threadIdx.x >> 6;
    int wpb = blockDim.x >> 6;
    int wstride = gridDim.x * wpb;
    int H2 = 2 * H;
    for (int n = blockIdx.x * wpb + wib; n < N; n += wstride) {
        float x = in[(size_t)n * 64 + lane];
        const float* wrow = Walr + lane * H2;
        for (int h = 0; h < H2; ++h) {
            float s = x * wrow[h];
            for (int off = 32; off; off >>= 1) s += __shfl_down(s, off);
            if (lane == 0) {
                if (h < H) el[(size_t)n * H + h] = s;
                else       er[(size_t)n * H + h - H] = s;
            }
        }
    }
}

// ---------- CSR build ----------
__global__ void count_deg(const int* __restrict__ dst, int* __restrict__ deg, int E) {
    int stride = gridDim.x * blockDim.x;
    for (int i = blockIdx.x * blockDim.x + threadIdx.x; i < E; i += stride)
        atomicAdd(&deg[dst[i]], 1);
}

__global__ void build_rowptr(const int* __restrict__ deg, int* __restrict__ rowptr, int N) {
    __shared__ int ssum[1024];
    int t = threadIdx.x;
    int nt = blockDim.x;
    int chunk = (N + nt - 1) / nt;
    int beg = t * chunk;
    int end = beg + chunk; if (end > N) end = N; if (beg > N) beg = N;
    int s = 0;
    for (int i = beg; i < end; ++i) s += deg[i];
    ssum[t] = s;
    __syncthreads();
    for (int off = 1; off < nt; off <<= 1) {
        int v = (t >= off) ? ssum[t - off] : 0;
        __syncthreads();
        ssum[t] += v;
        __syncthreads();
    }
    int run = (t == 0) ? 0 : ssum[t - 1];
    for (int i = beg; i < end; ++i) { rowptr[i] = run; run += deg[i]; }
    if (t == nt - 1) rowptr[N] = run;
}

__global__ void fill_adj(const int* __restrict__ src, const int* __restrict__ dst,
                         int* __restrict__ cursor, int* __restrict__ adj, int E) {
    int stride = gridDim.x * blockDim.x;
    for (int i = blockIdx.x * blockDim.x + threadIdx.x; i < E; i += stride) {
        int pos = atomicAdd(&cursor[dst[i]], 1);
        adj[pos] = src[i];
    }
}

// ---------- per-node softmax weights: ONE THREAD per node ----------
// el/er tables are L2-resident (<=1.6 MB). Online max/denominator, then a
// second sweep writes normalized alpha[j*H+h] per CSR slot.
template <int H>
__global__ void node_alpha(const int* __restrict__ rowptr, const int* __restrict__ adj,
                           const float* __restrict__ el, const float* __restrict__ er,
                           float* __restrict__ alpha, int N) {
    int stride = gridDim.x * blockDim.x;
    for (int n = blockIdx.x * blockDim.x + threadIdx.x; n < N; n += stride) {
        int rbeg = rowptr[n], rend = rowptr[n + 1];
        if (rbeg == rend) continue;
        float erh[H], m[H], den[H];
#pragma unroll
        for (int h = 0; h < H; ++h) {
            erh[h] = er[(size_t)n * H + h];
            m[h] = -INFINITY;
            den[h] = 0.f;
        }
        for (int j = rbeg; j < rend; ++j) {
            int s = adj[j];
            const float* els = el + (size_t)s * H;
#pragma unroll
            for (int h = 0; h < H; ++h) {
                float e = lrelu(els[h] + erh[h]);
                float newm = fmaxf(m[h], e);
                den[h] = den[h] * __expf(m[h] - newm) + __expf(e - newm);
                m[h] = newm;
            }
        }
        float inv[H];
#pragma unroll
        for (int h = 0; h < H; ++h) inv[h] = 1.f / fmaxf(den[h], 1e-9f);
        for (int j = rbeg; j < rend; ++j) {
            int s = adj[j];
            const float* els = el + (size_t)s * H;
#pragma unroll
            for (int h = 0; h < H; ++h) {
                float e = lrelu(els[h] + erh[h]);
                alpha[(size_t)j * H + h] = __expf(e - m[h]) * inv[h];
            }
        }
    }
}

// ---------- pure gather: wave per node, alpha precomputed ----------
// per edge: scalar src + alpha row, H*DV coalesced 256B loads, H*DV fmas.
template <int H, int DV>
__global__ __launch_bounds__(256, 8) void gat_gather3(
        const int* __restrict__ rowptr, const int* __restrict__ adj,
        const float* __restrict__ alpha, const float* __restrict__ feat,
        const float* __restrict__ bias, float* __restrict__ out,
        const int* __restrict__ gid, unsigned* __restrict__ gk, int N) {
    const int D = DV * 64;
    int lane = threadIdx.x & 63;
    int w = threadIdx.x >> 6;
    int wpb = blockDim.x >> 6;
    int wstride = gridDim.x * wpb;
    for (int n = blockIdx.x * wpb + w; n < N; n += wstride) {
        int rbeg = __builtin_amdgcn_readfirstlane(rowptr[n]);
        int rend = __builtin_amdgcn_readfirstlane(rowptr[n + 1]);
        float acc[H][DV];
#pragma unroll
        for (int h = 0; h < H; ++h)
#pragma unroll
            for (int v = 0; v < DV; ++v) acc[h][v] = 0.f;
        for (int j = rbeg; j < rend; ++j) {
            int s = __builtin_amdgcn_readfirstlane(adj[j]);
            const float* fs = feat + (size_t)s * (H * D);
            const float* al = alpha + (size_t)j * H;
#pragma unroll
            for (int h = 0; h < H; ++h) {
                float a = al[h];
#pragma unroll
                for (int v = 0; v < DV; ++v)
                    acc[h][v] += a * fs[h * D + v * 64 + lane];
            }
        }
        if (gid == nullptr) {
            float o[DV];
#pragma unroll
            for (int v = 0; v < DV; ++v) o[v] = 0.f;
#pragma unroll
            for (int h = 0; h < H; ++h) {
#pragma unroll
                for (int v = 0; v < DV; ++v) {
                    float val = acc[h][v] + bias[h * D + v * 64 + lane];
                    o[v] += val > 0.f ? val : 0.f;
                }
            }
#pragma unroll
            for (int v = 0; v < DV; ++v)
                out[(size_t)n * D + v * 64 + lane] = o[v];
        } else {
            int g = gid[n];
#pragma unroll
            for (int h = 0; h < H; ++h) {
#pragma unroll
                for (int v = 0; v < DV; ++v) {
                    float val = acc[h][v] + bias[h * D + v * 64 + lane];
                    val = val > 0.f ? val : 0.f;
                    atomicMax(&gk[(size_t)g * D + v * 64 + lane], fkey(val));
                }
            }
        }
    }
}

// ---------- head MLP ----------
__global__ void mlp_head(const unsigned* __restrict__ gkl, const unsigned* __restrict__ gkr,
                         const float* __restrict__ W1, const float* __restrict__ b1,
                         const float* __restrict__ W2, const float* __restrict__ b2,
                         float* __restrict__ out) {
    __shared__ float hcat[32][256];
    __shared__ float h[32][128];
    int t = threadIdx.x;  // 256 threads
    for (int i = t; i < 32 * 128; i += 256) {
        int r = i / 128, c = i % 128;
        unsigned kl = gkl[i];
        unsigned kr = gkr[i];
        hcat[r][c] = (kl == 0u) ? 0.f : funkey(kl);
        hcat[r][128 + c] = (kr == 0u) ? 0.f : funkey(kr);
    }
    __syncthreads();
    for (int i = t; i < 32 * 128; i += 256) {
        int r = i / 128, c = i % 128;
        float acc = b1[c];
        for (int k = 0; k < 256; ++k) acc += hcat[r][k] * W1[k * 128 + c];
        h[r][c] = acc > 0.f ? acc : 0.f;
    }
    __syncthreads();
    if (t < 32) {
        float acc = b2[0];
        for (int k = 0; k < 128; ++k) acc += h[t][k] * W2[k];
        out[t] = acc > 0.f ? acc : 0.f;
    }
}

// ---------- launch ----------
static inline unsigned nblk_elem(long long total) {
    long long b = (total + 255) / 256;
    if (b > 65535) b = 65535;
    if (b < 1) b = 1;
    return (unsigned)b;
}
static inline unsigned nblk_gather(long long nodes) {
    long long b = (nodes + 3) / 4;
    if (b > 65535) b = 65535;
    if (b < 1) b = 1;
    return (unsigned)b;
}

extern "C" void kernel_launch(void* const* d_in, const int* in_sizes, int n_in,
                              void* d_out, int out_size, void* d_ws, size_t ws_size,
                              hipStream_t stream) {
    const float* lig_x = (const float*)d_in[0];
    const int* lig_src = (const int*)d_in[1];
    const int* lig_dst = (const int*)d_in[2];
    const int* lig_gid = (const int*)d_in[3];
    const float* rec_x = (const float*)d_in[4];
    const int* rec_src = (const int*)d_in[5];
    const int* rec_dst = (const int*)d_in[6];
    const int* rec_gid = (const int*)d_in[7];
    const float* W1l = (const float*)d_in[8];
    const float* al1l = (const float*)d_in[9];
    const float* ar1l = (const float*)d_in[10];
    const float* b1l = (const float*)d_in[11];
    const float* W2l = (const float*)d_in[12];
    const float* al2l = (const float*)d_in[13];
    const float* ar2l = (const float*)d_in[14];
    const float* b2l = (const float*)d_in[15];
    const float* W1r = (const float*)d_in[16];
    const float* al1r = (const float*)d_in[17];
    const float* ar1r = (const float*)d_in[18];
    const float* b1r = (const float*)d_in[19];
    const float* W2r = (const float*)d_in[20];
    const float* al2r = (const float*)d_in[21];
    const float* ar2r = (const float*)d_in[22];
    const float* b2r = (const float*)d_in[23];
    const float* Wlin1 = (const float*)d_in[24];
    const float* blin1 = (const float*)d_in[25];
    const float* Wlin2 = (const float*)d_in[26];
    const float* blin2 = (const float*)d_in[27];

    int Nl = in_sizes[0] / 64, El = in_sizes[1];
    int Nr = in_sizes[4] / 64, Er = in_sizes[5];
    long long Nmax = Nl > Nr ? Nl : Nr;
    long long Emax = El > Er ? El : Er;

    // workspace layout
    char* ws = (char*)d_ws;
    float* feat = (float*)ws;        ws += Nmax * 640 * 4;   // layer1 feat; aliased as feat2
    float* h1 = (float*)ws;          ws += Nmax * 64 * 4;
    float* elb = (float*)ws;         ws += Nmax * 10 * 4;
    float* erb = (float*)ws;         ws += Nmax * 10 * 4;
    int* deg = (int*)ws;             ws += Nmax * 4;
    int* cursor = (int*)ws;          ws += Nmax * 4;
    int* rowptr = (int*)ws;          ws += (Nmax + 1) * 4;
    int* adj = (int*)ws;             ws += Emax * 4;
    float* alpha = (float*)ws;       ws += Emax * 10 * 4;
    unsigned* gkl = (unsigned*)ws;   ws += 32 * 128 * 4;
    unsigned* gkr = (unsigned*)ws;   ws += 32 * 128 * 4;
    float* Walr = (float*)ws;        ws += 64 * 32 * 4;
    float* feat2 = feat;  // [N,128]

    hipMemsetAsync(gkl, 0, 32 * 128 * 4, stream);
    hipMemsetAsync(gkr, 0, 32 * 128 * 4, stream);

    auto run_branch = [&](const float* x, const int* src, const int* dst, const int* gid,
                          const float* W1, const float* al1, const float* ar1, const float* b1,
                          const float* W2, const float* al2, const float* ar2, const float* b2,
                          unsigned* gk, int N, int E) {
        // CSR (shared by both layers)
        hipMemsetAsync(deg, 0, (size_t)N * 4, stream);
        count_deg<<<nblk_elem(E), 256, 0, stream>>>(dst, deg, E);
        build_rowptr<<<1, 1024, 0, stream>>>(deg, rowptr, N);
        hipMemcpyAsync(cursor, rowptr, (size_t)N * 4, hipMemcpyDeviceToDevice, stream);
        fill_adj<<<nblk_elem(E), 256, 0, stream>>>(src, dst, cursor, adj, E);

        // ---- layer 1: H=10, D=64 ----
        gemm_tiled<<<dim3((N + 63) / 64, 10), 256, 0, stream>>>(x, W1, feat, N, 640);
        fold_attn<<<64, 64, 0, stream>>>(W1, al1, ar1, Walr, 10, 64);
        attn_from_x<<<nblk_gather(N), 256, 0, stream>>>(x, Walr, elb, erb, N, 10);
        node_alpha<10><<<nblk_elem(N), 256, 0, stream>>>(rowptr, adj, elb, erb, alpha, N);
        gat_gather3<10, 1><<<nblk_gather(N), 256, 0, stream>>>(rowptr, adj, alpha, feat, b1,
                                                               h1, nullptr, nullptr, N);
        // ---- layer 2: H=1, D=128 ----
        gemm_tiled<<<dim3((N + 63) / 64, 2), 256, 0, stream>>>(h1, W2, feat2, N, 128);
        fold_attn<<<64, 64, 0, stream>>>(W2, al2, ar2, Walr, 1, 128);
        attn_from_x<<<nblk_gather(N), 256, 0, stream>>>(h1, Walr, elb, erb, N, 1);
        node_alpha<1><<<nblk_elem(N), 256, 0, stream>>>(rowptr, adj, elb, erb, alpha, N);
        gat_gather3<1, 2><<<nblk_gather(N), 256, 0, stream>>>(rowptr, adj, alpha, feat2, b2,
                                                              nullptr, gid, gk, N);
    };

    run_branch(lig_x, lig_src, lig_dst, lig_gid, W1l, al1l, ar1l, b1l, W2l, al2l, ar2l, b2l,
               gkl, Nl, El);
    run_branch(rec_x, rec_src, rec_dst, rec_gid, W1r, al1r, ar1r, b1r, W2r, al2r, ar2r, b2r,
               gkr, Nr, Er);

    mlp_head<<<1, 256, 0, stream>>>(gkl, gkr, Wlin1, blin1, Wlin2, blin2, (float*)d_out);
}